// Round 16
// baseline (380.397 us; speedup 1.0000x reference)
//
#include <hip/hip_runtime.h>
#include <hip/hip_bf16.h>
#include <math.h>

#define DEV __device__ __forceinline__

typedef __attribute__((ext_vector_type(4))) float f32x4;
typedef __attribute__((ext_vector_type(8))) __bf16 bf16x8;

// ---------------- problem constants ----------------
constexpr int N_CONST = 8192;
constexpr int E_CONST = 131072;

constexpr float SQ3F     = 1.7320508075688772f;
constexpr float INV_SQ3F = 0.57735026918962576f;
constexpr float FAN_TP   = 0.20412414523193150f;   // 24^-0.5
constexpr float FAN_TP_V = 0.35355339059327373f;   // sqrt(3)*24^-0.5
constexpr float FAN_DOT  = 0.11180339887498949f;   // 80^-0.5
constexpr float INV16SQ  = 0.25f;                  // 16^-0.5
constexpr float INV8SQ   = 0.35355339059327373f;   // 8^-0.5
constexpr float HID_SC   = 0.125f;                 // 64^-0.5

// ---------------- workspace layout (float offsets) ----------------
enum : int {
  OFF_LIN0 = 0,
  OFF_LIN1 = OFF_LIN0 + 256,
  OFF_HQ0  = OFF_LIN1 + 64,
  OFF_HQ1  = OFF_HQ0 + 256,
  OFF_FCK1 = OFF_HQ1 + 64,
  OFF_FCK2 = OFF_FCK1 + 2048,
  OFF_FCV1 = OFF_FCK2 + 36864,
  OFF_FCV2 = OFF_FCV1 + 2048,
  OFF_DOT0 = OFF_FCV2 + 73728,
  OFF_DOT1 = OFF_DOT0 + 128,
  OFF_RB0  = OFF_DOT1 + 32,
  OFF_RB1  = OFF_RB0 + 128,
  OFF_RE0  = OFF_RB1 + 32,
  OFF_RE1  = OFF_RE0 + 128,
  OFF_F    = OFF_RE1 + 32,
  OFF_POS  = OFF_F + N_CONST * 40,
  OFF_X    = OFF_POS + N_CONST * 3,
  OFF_Q    = OFF_X + N_CONST * 40,
  OFF_MX   = OFF_Q + N_CONST * 20,
  OFF_Z    = OFF_MX + N_CONST,
  OFF_AGG  = OFF_Z + N_CONST,
  OFF_LOGIT= OFF_AGG + N_CONST * 40,
  OFF_CUT  = OFF_LOGIT + E_CONST,
  OFF_EX   = OFF_CUT + E_CONST,
  OFF_FLAG = OFF_EX + E_CONST,     // int flag in a float slot
  OFF_WT   = (OFF_FLAG + 7) & ~3,  // bf16 WtV [2][36 tiles][1024] (swizzled)
  OFF_WTK  = OFF_WT + 36864,       // bf16 WtK [2][18 tiles][1024] (swizzled)
};

// ---------------- dtype detection ----------------
__global__ void k_detect(const unsigned int* __restrict__ words, int* __restrict__ flag) {
  if (blockIdx.x != 0 || threadIdx.x != 0) return;
  int cnt = 0;
  for (int i = 0; i < 512; ++i) {
    unsigned b = (words[i] >> 8) & 0x7Fu;
    cnt += (b >= 0x3Au && b <= 0x43u) ? 1 : 0;
  }
  *flag = (cnt > 256) ? 1 : 0;
}

// ---------------- convert all float inputs to f32 in ws ----------------
struct CvtArgs {
  const void* src[16];
  int n[16];
  int off[16];
};

template <bool BF>
__global__ void k_cvt(CvtArgs a, float* __restrict__ ws, const int* __restrict__ flag) {
  if ((*flag != 0) != BF) return;
  int tid = blockIdx.x * blockDim.x + threadIdx.x;
  int stride = gridDim.x * blockDim.x;
  for (int arr = 0; arr < 16; ++arr) {
    float* dst = ws + a.off[arr];
    int n = a.n[arr];
    if (BF) {
      const __hip_bfloat16* s = (const __hip_bfloat16*)a.src[arr];
      for (int i = tid; i < n; i += stride) dst[i] = __bfloat162float(s[i]);
    } else {
      const float* s = (const float*)a.src[arr];
      for (int i = tid; i < n; i += stride) dst[i] = s[i];
    }
  }
}

// ---------------- helpers ----------------
DEV unsigned short f2bf(float f) {   // RNE f32 -> bf16 bits
  unsigned int u = __float_as_uint(f);
  u = u + 0x7FFFu + ((u >> 16) & 1u);
  return (unsigned short)(u >> 16);
}

DEV void atomicMaxF(float* addr, float val) {
  unsigned int* ai = (unsigned int*)addr;
  unsigned int old = *ai;
  while (__uint_as_float(old) < val) {
    unsigned int assumed = old;
    old = atomicCAS(ai, assumed, __float_as_uint(val));
    if (old == assumed) break;
  }
}

template <int MO0, int MO1>
DEV void lin_apply(const float* __restrict__ in40, const float* __restrict__ W0,
                   const float* __restrict__ W1, float* __restrict__ out) {
#pragma unroll
  for (int j = 0; j < MO0; ++j) {
    float a = 0.f;
#pragma unroll
    for (int i = 0; i < 16; ++i) a += in40[i] * W0[i * MO0 + j];
    out[j] = a * INV16SQ;
  }
#pragma unroll
  for (int w = 0; w < MO1; ++w) {
    float a0 = 0.f, a1 = 0.f, a2 = 0.f;
#pragma unroll
    for (int u = 0; u < 8; ++u) {
      float wt = W1[u * MO1 + w];
      a0 += in40[16 + u * 3 + 0] * wt;
      a1 += in40[16 + u * 3 + 1] * wt;
      a2 += in40[16 + u * 3 + 2] * wt;
    }
    out[MO0 + w * 3 + 0] = a0 * INV8SQ;
    out[MO0 + w * 3 + 1] = a1 * INV8SQ;
    out[MO0 + w * 3 + 2] = a2 * INV8SQ;
  }
}

DEV void edge_emb(float d, float emb[16]) {
#pragma unroll
  for (int i = 0; i < 16; ++i) {
    float c = (2.0f * (i + 1)) / 17.0f;
    float df = (d - c) * (17.0f * 0.5f);
    emb[i] = __expf(-df * df) * (4.0f / 1.12f);
  }
}

// h for k in [khalf*32, khalf*32+32); khalf wave-uniform
DEV void radial_hidden32(const float* __restrict__ W1, const float emb[16],
                         int khalf, float h[32]) {
#pragma unroll 4
  for (int i = 0; i < 32; ++i) {
    float a = 0.f;
#pragma unroll
    for (int j = 0; j < 16; ++j) a += emb[j] * W1[j * 64 + khalf * 32 + i];
    a *= INV16SQ;
    float sig = 1.0f / (1.0f + __expf(-a));
    h[i] = a * sig * HID_SC;
  }
}

DEV void pack32(unsigned short* __restrict__ dst, const float h[32]) {
  unsigned int hw[16];
#pragma unroll
  for (int i = 0; i < 16; ++i)
    hw[i] = (unsigned int)f2bf(h[2 * i]) | ((unsigned int)f2bf(h[2 * i + 1]) << 16);
#pragma unroll
  for (int qq = 0; qq < 4; ++qq) {
    uint4 w = {hw[4 * qq], hw[4 * qq + 1], hw[4 * qq + 2], hw[4 * qq + 3]};
    *(uint4*)(dst + 8 * qq) = w;
  }
}

// ---------------- weight transposes to bf16 (slot-swizzled tiles) ----------------
__global__ void k_wt(const float* __restrict__ fcv2, unsigned short* __restrict__ wt) {
  int tid = blockIdx.x * blockDim.x + threadIdx.x;
  if (tid >= 2 * 36864) return;
  int l = tid / 36864;
  int r = tid - l * 36864;
  int T = r >> 10;
  int w = r & 1023;
  int c = w >> 6;
  int q = w & 63;
  int slot = (q >> 3) ^ (c & 7);
  int k = slot * 8 + (q & 7);
  wt[tid] = f2bf(fcv2[l * 36864 + k * 576 + T * 16 + c]);
}

__global__ void k_wtk(const float* __restrict__ fck2, unsigned short* __restrict__ wtk) {
  int tid = blockIdx.x * blockDim.x + threadIdx.x;
  if (tid >= 2 * 18432) return;
  int l = tid / 18432;
  int r = tid - l * 18432;
  int T = r >> 10;
  int w = r & 1023;
  int c = w >> 6;
  int q = w & 63;
  int slot = (q >> 3) ^ (c & 7);
  int k = slot * 8 + (q & 7);
  wtk[tid] = f2bf(fck2[l * 18432 + k * 288 + T * 16 + c]);
}

// ---------------- node kernels ----------------
__global__ void k_lin_in(const float* __restrict__ f, const float* __restrict__ W0,
                         const float* __restrict__ W1, float* __restrict__ x, int N) {
  int n = blockIdx.x * blockDim.x + threadIdx.x;
  if (n >= N) return;
  lin_apply<16, 8>(f + n * 40, W0, W1, x + n * 40);
}

// fused: x += agg (optional), then q = lin(x)
__global__ void k_qup(float* __restrict__ x, const float* __restrict__ agg,
                      const float* __restrict__ W0, const float* __restrict__ W1,
                      float* __restrict__ q, int N, int doAdd) {
  int n = blockIdx.x * blockDim.x + threadIdx.x;
  if (n >= N) return;
  float xn[40];
  if (doAdd) {
#pragma unroll
    for (int i = 0; i < 40; ++i) {
      xn[i] = x[n * 40 + i] + agg[n * 40 + i];
      x[n * 40 + i] = xn[i];
    }
  } else {
#pragma unroll
    for (int i = 0; i < 40; ++i) xn[i] = x[n * 40 + i];
  }
  lin_apply<8, 4>(xn, W0, W1, q + n * 20);
}

__global__ void k_init(float* __restrict__ mx, float* __restrict__ z,
                       float* __restrict__ agg, int N) {
  int i = blockIdx.x * blockDim.x + threadIdx.x;
  if (i < N * 40) agg[i] = 0.f;
  if (i < N) { mx[i] = -INFINITY; z[i] = 0.f; }
}

// ---------------- edge kernel 2: exp + denominator ----------------
__global__ void k_edge_ex(const int* __restrict__ dstv, const float* __restrict__ logit,
                          const float* __restrict__ cutb, const float* __restrict__ mx,
                          float* __restrict__ ex, float* __restrict__ z, int E) {
  int e = blockIdx.x * blockDim.x + threadIdx.x;
  if (e >= E) return;
  int t = dstv[e];
  float m = mx[t];
  if (m == -INFINITY) m = 0.f;
  float v = cutb[e] * __expf(logit[e] - m);
  ex[e] = v;
  atomicAdd(&z[t], v);
}

// =========================================================================
// Edge kernels: 128 threads = 2 waves, 64 edges. Wave wv owns M-tiles
// {2wv, 2wv+1} (rows [32wv, 32wv+32)). Weights LDS-staged, double-buffered.
// Each B-fragment read feeds 4 MFMAs (2 M-tiles x 2 K-steps).
// =========================================================================

// ---------------- edge kernel 1: K path + logits ----------------
// 18 tiles, 9 phases x 2 tiles; wave wv stages tile 2p+wv each phase.
__global__ void __launch_bounds__(128)
k_edge_k(const float* __restrict__ pos, const float* __restrict__ x,
         const float* __restrict__ q,
         const float* __restrict__ fck1, const unsigned short* __restrict__ wtk,
         const float* __restrict__ dot0, const float* __restrict__ dot1,
         const int* __restrict__ srcv, const int* __restrict__ dstv,
         float* __restrict__ logit, float* __restrict__ cutb,
         float* __restrict__ mx, int E) {
  __shared__ alignas(16) unsigned short h_lds[64 * 72];
  __shared__ alignas(16) unsigned short wbuf[2 * 2 * 1024];  // 2 buf x 2 tiles
  __shared__ float fS[48][64];   // fs 0..15 | fv 16..39 | vy 40..47
  __shared__ float y1A[64][4];
  __shared__ float qdA[64][8];
  __shared__ float qvA[64][12];
  __shared__ int dstA[64];

  const int tid = threadIdx.x;
  const int wv = __builtin_amdgcn_readfirstlane(tid >> 6);
  const int lane = tid & 63;
  const int e0 = blockIdx.x * 64;
  const int eL = e0 + lane;
  const bool valid = eL < E;

  // phase-0 preload: wave wv stages tile wv
  uint4 pre0, pre1;
  {
    const unsigned short* gs = wtk + wv * 1024 + lane * 8;
    pre0 = *(const uint4*)(gs);
    pre1 = *(const uint4*)(gs + 512);
  }

  int s = valid ? srcv[eL] : 0, t = valid ? dstv[eL] : 0;

  float y1v[3], d;
  {
    float vx = pos[s * 3 + 0] - pos[t * 3 + 0];
    float vy_ = pos[s * 3 + 1] - pos[t * 3 + 1];
    float vz = pos[s * 3 + 2] - pos[t * 3 + 2];
    d = sqrtf(vx * vx + vy_ * vy_ + vz * vz + 1e-24f);
    float inv = SQ3F / d;
    y1v[0] = vx * inv; y1v[1] = vy_ * inv; y1v[2] = vz * inv;
  }
  float emb[16];
  edge_emb(d, emb);
  {
    float h[32];
    radial_hidden32(fck1, emb, wv, h);
    pack32(&h_lds[lane * 72 + 32 * wv], h);
  }

  if (wv == 0) {
    const float* xs = x + s * 40;
    float fvl[24];
#pragma unroll
    for (int i = 0; i < 16; ++i) fS[i][lane] = xs[i];
#pragma unroll
    for (int i = 0; i < 24; ++i) { fvl[i] = xs[16 + i]; fS[16 + i][lane] = fvl[i]; }
#pragma unroll
    for (int u = 0; u < 8; ++u)
      fS[40 + u][lane] = (fvl[u * 3] * y1v[0] + fvl[u * 3 + 1] * y1v[1] +
                          fvl[u * 3 + 2] * y1v[2]) * INV_SQ3F;
    y1A[lane][0] = y1v[0]; y1A[lane][1] = y1v[1]; y1A[lane][2] = y1v[2];
    dstA[lane] = t;
    if (valid) {
      float uu = 10.0f * (1.0f - 0.5f * d);
      cutb[eL] = (uu > 0.f) ? __expf(-1.0f / fmaxf(uu, 1e-9f)) : 0.f;
    }
    const float* qd_ = q + t * 20;
    float qs_[8], qv_[12];
#pragma unroll
    for (int u = 0; u < 8; ++u) qs_[u] = qd_[u];
#pragma unroll
    for (int i = 0; i < 12; ++i) qv_[i] = qd_[8 + i];
#pragma unroll
    for (int v = 0; v < 8; ++v) {
      float a = 0.f;
#pragma unroll
      for (int u = 0; u < 8; ++u) a += qs_[u] * dot0[u * 8 + v];
      qdA[lane][v] = a * (FAN_DOT * FAN_TP);
    }
#pragma unroll
    for (int v = 0; v < 4; ++v)
#pragma unroll
      for (int i = 0; i < 3; ++i) {
        float a = 0.f;
#pragma unroll
        for (int u = 0; u < 4; ++u) a += qv_[u * 3 + i] * dot1[u * 4 + v];
        qvA[lane][v * 3 + i] = a * (FAN_DOT * INV_SQ3F);
      }
  }
  {
    unsigned short* wd = wbuf + wv * 1024 + lane * 8;
    *(uint4*)(wd) = pre0;
    *(uint4*)(wd + 512) = pre1;
  }
  __syncthreads();

  const int c = lane & 15, g = lane >> 4;
  const f32x4 zero4 = {0.f, 0.f, 0.f, 0.f};

  bf16x8 aK[2][2];
#pragma unroll
  for (int m = 0; m < 2; ++m)
#pragma unroll
    for (int ks = 0; ks < 2; ++ks)
      aK[m][ks] = __builtin_bit_cast(
          bf16x8, *(const uint4*)&h_lds[(32 * wv + 16 * m + c) * 72 + 32 * ks + 8 * g]);

  float ksp[2][4] = {{0.f}}, a2p[2][4] = {{0.f}}, a3p[2][4][3] = {{{0.f}}};

#pragma unroll 1
  for (int p = 0; p < 9; ++p) {
    uint4 nb0, nb1;
    const bool hasNext = (p < 8);
    if (hasNext) {
      const unsigned short* gs = wtk + (2 * (p + 1) + wv) * 1024 + lane * 8;
      nb0 = *(const uint4*)(gs);
      nb1 = *(const uint4*)(gs + 512);
    }
    const unsigned short* wb = wbuf + (p & 1) * 2048;
#pragma unroll
    for (int t2 = 0; t2 < 2; ++t2) {
      int T = 2 * p + t2;
      int s0 = g ^ (c & 7);
      const unsigned short* wtile = wb + t2 * 1024 + c * 64;
      bf16x8 b0 = __builtin_bit_cast(bf16x8, *(const uint4*)(wtile + s0 * 8));
      bf16x8 b1 = __builtin_bit_cast(bf16x8, *(const uint4*)(wtile + (s0 ^ 4) * 8));
#pragma unroll
      for (int m = 0; m < 2; ++m) {
        f32x4 acc = __builtin_amdgcn_mfma_f32_16x16x32_bf16(aK[m][0], b0, zero4, 0, 0, 0);
        acc = __builtin_amdgcn_mfma_f32_16x16x32_bf16(aK[m][1], b1, acc, 0, 0, 0);
        const int rb = 32 * wv + 16 * m + 4 * g;
        if (T < 8) {
          int u = 2 * T + (c >> 3);
#pragma unroll
          for (int j = 0; j < 4; ++j) ksp[m][j] += fS[u][rb + j] * acc[j];
        } else if (T < 12) {
          int u = 4 * (T - 8) + (c >> 2);
#pragma unroll
          for (int j = 0; j < 4; ++j) a2p[m][j] += fS[u][rb + j] * acc[j];
        } else if (T < 14) {
          int u = 4 * (T - 12) + (c >> 2);
#pragma unroll
          for (int j = 0; j < 4; ++j)
#pragma unroll
            for (int i = 0; i < 3; ++i) a3p[m][j][i] += fS[16 + u * 3 + i][rb + j] * acc[j];
        } else {
          int u = 2 * (T - 14) + (c >> 3);
#pragma unroll
          for (int j = 0; j < 4; ++j) ksp[m][j] += fS[40 + u][rb + j] * acc[j];
        }
      }
    }
    if (hasNext) {
      unsigned short* wd = wbuf + ((p + 1) & 1) * 2048 + wv * 1024 + lane * 8;
      *(uint4*)(wd) = nb0;
      *(uint4*)(wd + 512) = nb1;
    }
    __syncthreads();
  }

#pragma unroll
  for (int m = 0; m < 2; ++m) {
    float ksf[4], a2f[4], a3f[4][3];
#pragma unroll
    for (int j = 0; j < 4; ++j) ksf[j] = ksp[m][j] + __shfl_xor(ksp[m][j], 8);
#pragma unroll
    for (int j = 0; j < 4; ++j) {
      float v = a2p[m][j] + __shfl_xor(a2p[m][j], 4);
      a2f[j] = v + __shfl_xor(v, 8);
    }
#pragma unroll
    for (int j = 0; j < 4; ++j)
#pragma unroll
      for (int i = 0; i < 3; ++i) {
        float v = a3p[m][j][i] + __shfl_xor(a3p[m][j][i], 4);
        a3f[j][i] = v + __shfl_xor(v, 8);
      }

    float lgp[4];
#pragma unroll
    for (int j = 0; j < 4; ++j) {
      int er = 32 * wv + 16 * m + 4 * g + j;
      float a = 0.f;
      if (c < 8) {
        a = ksf[j] * qdA[er][c];
      } else if (c < 12) {
        int w = c - 8;
#pragma unroll
        for (int i = 0; i < 3; ++i)
          a += (a2f[j] * y1A[er][i] * FAN_TP + a3f[j][i] * FAN_TP_V) * qvA[er][w * 3 + i];
      }
      lgp[j] = a;
      lgp[j] += __shfl_xor(lgp[j], 1);
      lgp[j] += __shfl_xor(lgp[j], 2);
      lgp[j] += __shfl_xor(lgp[j], 4);
      lgp[j] += __shfl_xor(lgp[j], 8);
    }
    if (c == 0) {
#pragma unroll
      for (int j = 0; j < 4; ++j) {
        int er = 32 * wv + 16 * m + 4 * g + j;
        int ee = e0 + er;
        if (ee < E) {
          logit[ee] = lgp[j];
          atomicMaxF(&mx[dstA[er]], lgp[j]);
        }
      }
    }
  }
}

// ---------------- edge kernel 3: V path + scatter ----------------
// 36 tiles, 9 phases x 4 tiles; wave wv stages tiles {4p+2wv, 4p+2wv+1}.
__global__ void __launch_bounds__(128)
k_edge_v(const float* __restrict__ pos, const float* __restrict__ x,
         const float* __restrict__ fcv1, const unsigned short* __restrict__ wtv,
         const int* __restrict__ srcv, const int* __restrict__ dstv,
         const float* __restrict__ ex, const float* __restrict__ z,
         float* __restrict__ agg, int E) {
  __shared__ alignas(16) unsigned short h_lds[64 * 72];
  __shared__ alignas(16) unsigned short wbuf[2 * 4 * 1024];  // 2 buf x 4 tiles
  __shared__ float fS[48][64];
  __shared__ float y1A[64][4];
  __shared__ float wgtA[64];
  __shared__ int dstA[64];

  const int tid = threadIdx.x;
  const int wv = __builtin_amdgcn_readfirstlane(tid >> 6);
  const int lane = tid & 63;
  const int e0 = blockIdx.x * 64;
  const int eL = e0 + lane;
  const bool valid = eL < E;

  // phase-0 preload: wave wv stages tiles 2wv, 2wv+1
  uint4 pre0, pre1, pre2, pre3;
  {
    const unsigned short* gs = wtv + (2 * wv) * 1024 + lane * 8;
    pre0 = *(const uint4*)(gs);
    pre1 = *(const uint4*)(gs + 512);
    pre2 = *(const uint4*)(gs + 1024);
    pre3 = *(const uint4*)(gs + 1536);
  }

  int s = valid ? srcv[eL] : 0, t = valid ? dstv[eL] : 0;

  float y1v[3], d;
  {
    float vx = pos[s * 3 + 0] - pos[t * 3 + 0];
    float vy_ = pos[s * 3 + 1] - pos[t * 3 + 1];
    float vz = pos[s * 3 + 2] - pos[t * 3 + 2];
    d = sqrtf(vx * vx + vy_ * vy_ + vz * vz + 1e-24f);
    float inv = SQ3F / d;
    y1v[0] = vx * inv; y1v[1] = vy_ * inv; y1v[2] = vz * inv;
  }
  float emb[16];
  edge_emb(d, emb);
  {
    float h[32];
    radial_hidden32(fcv1, emb, wv, h);
    pack32(&h_lds[lane * 72 + 32 * wv], h);
  }

  if (wv == 0) {
    const float* xs = x + s * 40;
    float fvl[24];
#pragma unroll
    for (int i = 0; i < 16; ++i) fS[i][lane] = xs[i];
#pragma unroll
    for (int i = 0; i < 24; ++i) { fvl[i] = xs[16 + i]; fS[16 + i][lane] = fvl[i]; }
#pragma unroll
    for (int u = 0; u < 8; ++u)
      fS[40 + u][lane] = (fvl[u * 3] * y1v[0] + fvl[u * 3 + 1] * y1v[1] +
                          fvl[u * 3 + 2] * y1v[2]) * INV_SQ3F;
    y1A[lane][0] = y1v[0]; y1A[lane][1] = y1v[1]; y1A[lane][2] = y1v[2];
    dstA[lane] = t;
    float zz = z[t];
    zz = (zz == 0.f) ? 1.f : zz;
    float alpha = (valid ? ex[eL] : 0.f) / zz;
    wgtA[lane] = sqrtf(alpha + 1e-12f);
  }
  {
    unsigned short* wd = wbuf + (2 * wv) * 1024 + lane * 8;
    *(uint4*)(wd) = pre0;
    *(uint4*)(wd + 512) = pre1;
    *(uint4*)(wd + 1024) = pre2;
    *(uint4*)(wd + 1536) = pre3;
  }
  __syncthreads();

  const int c = lane & 15, g = lane >> 4;
  const f32x4 zero4 = {0.f, 0.f, 0.f, 0.f};

  bf16x8 aV[2][2];
#pragma unroll
  for (int m = 0; m < 2; ++m)
#pragma unroll
    for (int ks = 0; ks < 2; ++ks)
      aV[m][ks] = __builtin_bit_cast(
          bf16x8, *(const uint4*)&h_lds[(32 * wv + 16 * m + c) * 72 + 32 * ks + 8 * g]);

  float vs[2][4] = {{0.f}}, b2[2][4] = {{0.f}}, b3[2][4][3] = {{{0.f}}};

#pragma unroll 1
  for (int p = 0; p < 9; ++p) {
    uint4 nb0, nb1, nb2, nb3;
    const bool hasNext = (p < 8);
    if (hasNext) {
      const unsigned short* gs = wtv + (4 * (p + 1) + 2 * wv) * 1024 + lane * 8;
      nb0 = *(const uint4*)(gs);
      nb1 = *(const uint4*)(gs + 512);
      nb2 = *(const uint4*)(gs + 1024);
      nb3 = *(const uint4*)(gs + 1536);
    }
    const unsigned short* wb = wbuf + (p & 1) * 4096;
#pragma unroll
    for (int t2 = 0; t2 < 4; ++t2) {
      int T = 4 * p + t2;
      int s0 = g ^ (c & 7);
      const unsigned short* wtile = wb + t2 * 1024 + c * 64;
      bf16x8 b0 = __builtin_bit_cast(bf16x8, *(const uint4*)(wtile + s0 * 8));
      bf16x8 b1 = __builtin_bit_cast(bf16x8, *(const uint4*)(wtile + (s0 ^ 4) * 8));
#pragma unroll
      for (int m = 0; m < 2; ++m) {
        f32x4 acc = __builtin_amdgcn_mfma_f32_16x16x32_bf16(aV[m][0], b0, zero4, 0, 0, 0);
        acc = __builtin_amdgcn_mfma_f32_16x16x32_bf16(aV[m][1], b1, acc, 0, 0, 0);
        const int rb = 32 * wv + 16 * m + 4 * g;
        if (T < 16) {
#pragma unroll
          for (int j = 0; j < 4; ++j) vs[m][j] += fS[T][rb + j] * acc[j];
        } else if (T < 24) {
          int u = 2 * (T - 16) + (c >> 3);
#pragma unroll
          for (int j = 0; j < 4; ++j) b2[m][j] += fS[u][rb + j] * acc[j];
        } else if (T < 28) {
          int u = 2 * (T - 24) + (c >> 3);
#pragma unroll
          for (int j = 0; j < 4; ++j)
#pragma unroll
            for (int i = 0; i < 3; ++i) b3[m][j][i] += fS[16 + u * 3 + i][rb + j] * acc[j];
        } else {
#pragma unroll
          for (int j = 0; j < 4; ++j) vs[m][j] += fS[40 + (T - 28)][rb + j] * acc[j];
        }
      }
    }
    if (hasNext) {
      unsigned short* wd = wbuf + ((p + 1) & 1) * 4096 + (2 * wv) * 1024 + lane * 8;
      *(uint4*)(wd) = nb0;
      *(uint4*)(wd + 512) = nb1;
      *(uint4*)(wd + 1024) = nb2;
      *(uint4*)(wd + 1536) = nb3;
    }
    __syncthreads();
  }

#pragma unroll
  for (int m = 0; m < 2; ++m) {
#pragma unroll
    for (int j = 0; j < 4; ++j) b2[m][j] += __shfl_xor(b2[m][j], 8);
#pragma unroll
    for (int j = 0; j < 4; ++j)
#pragma unroll
      for (int i = 0; i < 3; ++i) b3[m][j][i] += __shfl_xor(b3[m][j][i], 8);

    // scatter: lane owns col c of the 4 edges in its (wv, m, g) row block
#pragma unroll
    for (int j = 0; j < 4; ++j) {
      int er = 32 * wv + 16 * m + 4 * g + j;
      int ee = e0 + er;
      if (ee >= E) continue;
      float w = wgtA[er];
      float* at = agg + dstA[er] * 40;
      atomicAdd(&at[c], w * vs[m][j] * FAN_TP);
      if (c < 8) {
#pragma unroll
        for (int i = 0; i < 2; ++i) {
          float v = b2[m][j] * y1A[er][i] * FAN_TP + b3[m][j][i] * FAN_TP_V;
          atomicAdd(&at[16 + c * 3 + i], w * v);
        }
      } else {
        float v = b2[m][j] * y1A[er][2] * FAN_TP + b3[m][j][2] * FAN_TP_V;
        atomicAdd(&at[16 + (c - 8) * 3 + 2], w * v);
      }
    }
  }
}

// ---------------- output kernel (fused final x += agg) ----------------
template <bool BF>
__global__ void k_out(const float* __restrict__ x, const float* __restrict__ agg,
                      const float* __restrict__ rb0, const float* __restrict__ rb1,
                      const float* __restrict__ re0, const float* __restrict__ re1,
                      void* __restrict__ out, int N, const int* __restrict__ flag) {
  if ((*flag != 0) != BF) return;
  int n = blockIdx.x * blockDim.x + threadIdx.x;
  if (n >= N) return;
  float xn[40];
#pragma unroll
  for (int i = 0; i < 40; ++i) xn[i] = x[n * 40 + i] + agg[n * 40 + i];
  float b[20], eta[20];
  lin_apply<8, 4>(xn, rb0, rb1, b);
  lin_apply<8, 4>(xn, re0, re1, eta);
  if (BF) {
    __hip_bfloat16* o = (__hip_bfloat16*)out;
#pragma unroll
    for (int j = 0; j < 20; ++j) o[n * 20 + j] = __float2bfloat16(b[j]);
#pragma unroll
    for (int j = 0; j < 20; ++j) o[N * 20 + n * 20 + j] = __float2bfloat16(eta[j]);
  } else {
    float* o = (float*)out;
#pragma unroll
    for (int j = 0; j < 20; ++j) o[n * 20 + j] = b[j];
#pragma unroll
    for (int j = 0; j < 20; ++j) o[N * 20 + n * 20 + j] = eta[j];
  }
}

// ---------------- host ----------------
extern "C" void kernel_launch(void* const* d_in, const int* in_sizes, int n_in,
                              void* d_out, int out_size, void* d_ws, size_t ws_size,
                              hipStream_t stream) {
  float* ws = (float*)d_ws;
  const int N = in_sizes[0] / 40;
  const int E = in_sizes[16];
  const int* src = (const int*)d_in[16];
  const int* dst = (const int*)d_in[17];
  int* flag = (int*)(ws + OFF_FLAG);
  unsigned short* wtv = (unsigned short*)(ws + OFF_WT);
  unsigned short* wtk = (unsigned short*)(ws + OFF_WTK);

  k_detect<<<1, 64, 0, stream>>>((const unsigned int*)d_in[0], flag);

  CvtArgs ca;
  const int order[16] = {2, 3, 4, 5, 6, 7, 8, 9, 10, 11, 12, 13, 14, 15, 0, 1};
  const int offs[16] = {OFF_LIN0, OFF_LIN1, OFF_HQ0, OFF_HQ1, OFF_FCK1, OFF_FCK2,
                        OFF_FCV1, OFF_FCV2, OFF_DOT0, OFF_DOT1, OFF_RB0, OFF_RB1,
                        OFF_RE0, OFF_RE1, OFF_F, OFF_POS};
  for (int i = 0; i < 16; ++i) {
    ca.src[i] = d_in[order[i]];
    ca.n[i] = in_sizes[order[i]];
    ca.off[i] = offs[i];
  }
  k_cvt<false><<<512, 256, 0, stream>>>(ca, ws, flag);
  k_cvt<true><<<512, 256, 0, stream>>>(ca, ws, flag);
  k_wt<<<(2 * 36864 + 255) / 256, 256, 0, stream>>>(ws + OFF_FCV2, wtv);
  k_wtk<<<(2 * 18432 + 255) / 256, 256, 0, stream>>>(ws + OFF_FCK2, wtk);

  float* x = ws + OFF_X;
  float* q = ws + OFF_Q;
  float* mx = ws + OFF_MX;
  float* z = ws + OFF_Z;
  float* agg = ws + OFF_AGG;
  float* logit = ws + OFF_LOGIT;
  float* cutb = ws + OFF_CUT;
  float* exb = ws + OFF_EX;
  const float* pos = ws + OFF_POS;

  const int nodeBlocks = (N + 255) / 256;
  const int vecBlocks = (N * 40 + 255) / 256;
  const int edgeBlocks = (E + 255) / 256;
  const int eb64 = (E + 63) / 64;   // block = 64 edges, 128 threads

  k_lin_in<<<nodeBlocks, 256, 0, stream>>>(ws + OFF_F, ws + OFF_LIN0, ws + OFF_LIN1, x, N);

  for (int l = 0; l < 2; ++l) {
    // x += agg(prev layer) fused into q computation; must precede k_init's agg clear
    k_qup<<<nodeBlocks, 256, 0, stream>>>(x, agg, ws + OFF_HQ0 + l * 128,
                                          ws + OFF_HQ1 + l * 32, q, N, l > 0 ? 1 : 0);
    k_init<<<vecBlocks, 256, 0, stream>>>(mx, z, agg, N);
    k_edge_k<<<eb64, 128, 0, stream>>>(
        pos, x, q, ws + OFF_FCK1 + l * 1024, wtk + l * 18432,
        ws + OFF_DOT0 + l * 64, ws + OFF_DOT1 + l * 16, src, dst, logit, cutb, mx, E);
    k_edge_ex<<<edgeBlocks, 256, 0, stream>>>(dst, logit, cutb, mx, exb, z, E);
    k_edge_v<<<eb64, 128, 0, stream>>>(
        pos, x, ws + OFF_FCV1 + l * 1024, wtv + l * 36864, src, dst, exb, z, agg, E);
  }

  k_out<false><<<nodeBlocks, 256, 0, stream>>>(x, agg, ws + OFF_RB0, ws + OFF_RB1,
                                               ws + OFF_RE0, ws + OFF_RE1, d_out, N, flag);
  k_out<true><<<nodeBlocks, 256, 0, stream>>>(x, agg, ws + OFF_RB0, ws + OFF_RB1,
                                              ws + OFF_RE0, ws + OFF_RE1, d_out, N, flag);
}

// Round 17
// 283.391 us; speedup vs baseline: 1.3423x; 1.3423x over previous
//
#include <hip/hip_runtime.h>
#include <hip/hip_bf16.h>
#include <math.h>

#define DEV __device__ __forceinline__

typedef __attribute__((ext_vector_type(4))) float f32x4;
typedef __attribute__((ext_vector_type(8))) __bf16 bf16x8;

// ---------------- problem constants ----------------
constexpr int N_CONST = 8192;
constexpr int E_CONST = 131072;

constexpr float SQ3F     = 1.7320508075688772f;
constexpr float INV_SQ3F = 0.57735026918962576f;
constexpr float FAN_TP   = 0.20412414523193150f;   // 24^-0.5
constexpr float FAN_TP_V = 0.35355339059327373f;   // sqrt(3)*24^-0.5
constexpr float FAN_DOT  = 0.11180339887498949f;   // 80^-0.5
constexpr float INV16SQ  = 0.25f;                  // 16^-0.5
constexpr float INV8SQ   = 0.35355339059327373f;   // 8^-0.5
constexpr float HID_SC   = 0.125f;                 // 64^-0.5

// ---------------- workspace layout (float offsets) ----------------
enum : int {
  OFF_LIN0 = 0,
  OFF_LIN1 = OFF_LIN0 + 256,
  OFF_HQ0  = OFF_LIN1 + 64,
  OFF_HQ1  = OFF_HQ0 + 256,
  OFF_FCK1 = OFF_HQ1 + 64,
  OFF_FCK2 = OFF_FCK1 + 2048,
  OFF_FCV1 = OFF_FCK2 + 36864,
  OFF_FCV2 = OFF_FCV1 + 2048,
  OFF_DOT0 = OFF_FCV2 + 73728,
  OFF_DOT1 = OFF_DOT0 + 128,
  OFF_RB0  = OFF_DOT1 + 32,
  OFF_RB1  = OFF_RB0 + 128,
  OFF_RE0  = OFF_RB1 + 32,
  OFF_RE1  = OFF_RE0 + 128,
  OFF_F    = OFF_RE1 + 32,
  OFF_POS  = OFF_F + N_CONST * 40,
  OFF_X    = OFF_POS + N_CONST * 3,
  OFF_Q    = OFF_X + N_CONST * 40,
  OFF_MX   = OFF_Q + N_CONST * 20,
  OFF_Z    = OFF_MX + N_CONST,
  OFF_AGG  = OFF_Z + N_CONST,
  OFF_LOGIT= OFF_AGG + N_CONST * 40,
  OFF_CUT  = OFF_LOGIT + E_CONST,
  OFF_EX   = OFF_CUT + E_CONST,
  OFF_FLAG = OFF_EX + E_CONST,     // int flag in a float slot
  OFF_WT   = (OFF_FLAG + 7) & ~3,  // bf16 WtV [2][36 tiles][1024] (swizzled)
  OFF_WTK  = OFF_WT + 36864,       // bf16 WtK [2][18 tiles][1024] (swizzled)
};

// ---------------- dtype detection ----------------
__global__ void k_detect(const unsigned int* __restrict__ words, int* __restrict__ flag) {
  if (blockIdx.x != 0 || threadIdx.x != 0) return;
  int cnt = 0;
  for (int i = 0; i < 512; ++i) {
    unsigned b = (words[i] >> 8) & 0x7Fu;
    cnt += (b >= 0x3Au && b <= 0x43u) ? 1 : 0;
  }
  *flag = (cnt > 256) ? 1 : 0;
}

// ---------------- convert all float inputs to f32 in ws ----------------
struct CvtArgs {
  const void* src[16];
  int n[16];
  int off[16];
};

template <bool BF>
__global__ void k_cvt(CvtArgs a, float* __restrict__ ws, const int* __restrict__ flag) {
  if ((*flag != 0) != BF) return;
  int tid = blockIdx.x * blockDim.x + threadIdx.x;
  int stride = gridDim.x * blockDim.x;
  for (int arr = 0; arr < 16; ++arr) {
    float* dst = ws + a.off[arr];
    int n = a.n[arr];
    if (BF) {
      const __hip_bfloat16* s = (const __hip_bfloat16*)a.src[arr];
      for (int i = tid; i < n; i += stride) dst[i] = __bfloat162float(s[i]);
    } else {
      const float* s = (const float*)a.src[arr];
      for (int i = tid; i < n; i += stride) dst[i] = s[i];
    }
  }
}

// ---------------- helpers ----------------
DEV unsigned short f2bf(float f) {   // RNE f32 -> bf16 bits
  unsigned int u = __float_as_uint(f);
  u = u + 0x7FFFu + ((u >> 16) & 1u);
  return (unsigned short)(u >> 16);
}

DEV void atomicMaxF(float* addr, float val) {
  unsigned int* ai = (unsigned int*)addr;
  unsigned int old = *ai;
  while (__uint_as_float(old) < val) {
    unsigned int assumed = old;
    old = atomicCAS(ai, assumed, __float_as_uint(val));
    if (old == assumed) break;
  }
}

template <int MO0, int MO1>
DEV void lin_apply(const float* __restrict__ in40, const float* __restrict__ W0,
                   const float* __restrict__ W1, float* __restrict__ out) {
#pragma unroll
  for (int j = 0; j < MO0; ++j) {
    float a = 0.f;
#pragma unroll
    for (int i = 0; i < 16; ++i) a += in40[i] * W0[i * MO0 + j];
    out[j] = a * INV16SQ;
  }
#pragma unroll
  for (int w = 0; w < MO1; ++w) {
    float a0 = 0.f, a1 = 0.f, a2 = 0.f;
#pragma unroll
    for (int u = 0; u < 8; ++u) {
      float wt = W1[u * MO1 + w];
      a0 += in40[16 + u * 3 + 0] * wt;
      a1 += in40[16 + u * 3 + 1] * wt;
      a2 += in40[16 + u * 3 + 2] * wt;
    }
    out[MO0 + w * 3 + 0] = a0 * INV8SQ;
    out[MO0 + w * 3 + 1] = a1 * INV8SQ;
    out[MO0 + w * 3 + 2] = a2 * INV8SQ;
  }
}

DEV void edge_emb(float d, float emb[16]) {
#pragma unroll
  for (int i = 0; i < 16; ++i) {
    float c = (2.0f * (i + 1)) / 17.0f;
    float df = (d - c) * (17.0f * 0.5f);
    emb[i] = __expf(-df * df) * (4.0f / 1.12f);
  }
}

// h for k in [wv*16, wv*16+16); wv wave-uniform
DEV void radial_hidden16(const float* __restrict__ W1, const float emb[16],
                         int wv, float h[16]) {
#pragma unroll 1
  for (int i = 0; i < 16; ++i) {
    float a = 0.f;
#pragma unroll
    for (int j = 0; j < 16; ++j) a += emb[j] * W1[j * 64 + wv * 16 + i];
    a *= INV16SQ;
    float sig = 1.0f / (1.0f + __expf(-a));
    h[i] = a * sig * HID_SC;
  }
}

DEV void pack16(unsigned short* __restrict__ dst, const float h[16]) {
  unsigned int hw[8];
#pragma unroll
  for (int i = 0; i < 8; ++i)
    hw[i] = (unsigned int)f2bf(h[2 * i]) | ((unsigned int)f2bf(h[2 * i + 1]) << 16);
  uint4 w0 = {hw[0], hw[1], hw[2], hw[3]};
  uint4 w1 = {hw[4], hw[5], hw[6], hw[7]};
  *(uint4*)(dst) = w0;
  *(uint4*)(dst + 8) = w1;
}

// B-frag from an LDS-staged, slot-swizzled 2KB weight tile.
// Tile layout (shorts): c*64 + ((k>>3)^(c&7))*8 + (k&7). Read slots s0=g^(c&7)
// (ks=0) and s0^4 (ks=1) recover the original k=32ks+8g+j ordering.
DEV f32x4 gemm2_lds(const unsigned short* __restrict__ wb, int c, int g,
                    bf16x8 a0, bf16x8 a1) {
  const f32x4 zero4 = {0.f, 0.f, 0.f, 0.f};
  int s0 = g ^ (c & 7);
  bf16x8 b0 = __builtin_bit_cast(bf16x8, *(const uint4*)(wb + c * 64 + s0 * 8));
  bf16x8 b1 = __builtin_bit_cast(bf16x8, *(const uint4*)(wb + c * 64 + (s0 ^ 4) * 8));
  f32x4 acc = __builtin_amdgcn_mfma_f32_16x16x32_bf16(a0, b0, zero4, 0, 0, 0);
  return __builtin_amdgcn_mfma_f32_16x16x32_bf16(a1, b1, acc, 0, 0, 0);
}

// ---------------- weight transposes to bf16 (slot-swizzled tiles) ----------------
__global__ void k_wt(const float* __restrict__ fcv2, unsigned short* __restrict__ wt) {
  int tid = blockIdx.x * blockDim.x + threadIdx.x;
  if (tid >= 2 * 36864) return;
  int l = tid / 36864;
  int r = tid - l * 36864;
  int T = r >> 10;
  int w = r & 1023;
  int c = w >> 6;
  int q = w & 63;
  int slot = (q >> 3) ^ (c & 7);
  int k = slot * 8 + (q & 7);
  wt[tid] = f2bf(fcv2[l * 36864 + k * 576 + T * 16 + c]);
}

__global__ void k_wtk(const float* __restrict__ fck2, unsigned short* __restrict__ wtk) {
  int tid = blockIdx.x * blockDim.x + threadIdx.x;
  if (tid >= 2 * 18432) return;
  int l = tid / 18432;
  int r = tid - l * 18432;
  int T = r >> 10;
  int w = r & 1023;
  int c = w >> 6;
  int q = w & 63;
  int slot = (q >> 3) ^ (c & 7);
  int k = slot * 8 + (q & 7);
  wtk[tid] = f2bf(fck2[l * 18432 + k * 288 + T * 16 + c]);
}

// ---------------- node kernels ----------------
__global__ void k_lin_in(const float* __restrict__ f, const float* __restrict__ W0,
                         const float* __restrict__ W1, float* __restrict__ x, int N) {
  int n = blockIdx.x * blockDim.x + threadIdx.x;
  if (n >= N) return;
  lin_apply<16, 8>(f + n * 40, W0, W1, x + n * 40);
}

// fused: x += agg (optional), then q = lin(x)
__global__ void k_qup(float* __restrict__ x, const float* __restrict__ agg,
                      const float* __restrict__ W0, const float* __restrict__ W1,
                      float* __restrict__ q, int N, int doAdd) {
  int n = blockIdx.x * blockDim.x + threadIdx.x;
  if (n >= N) return;
  float xn[40];
  if (doAdd) {
#pragma unroll
    for (int i = 0; i < 40; ++i) {
      xn[i] = x[n * 40 + i] + agg[n * 40 + i];
      x[n * 40 + i] = xn[i];
    }
  } else {
#pragma unroll
    for (int i = 0; i < 40; ++i) xn[i] = x[n * 40 + i];
  }
  lin_apply<8, 4>(xn, W0, W1, q + n * 20);
}

__global__ void k_init(float* __restrict__ mx, float* __restrict__ z,
                       float* __restrict__ agg, int N) {
  int i = blockIdx.x * blockDim.x + threadIdx.x;
  if (i < N * 40) agg[i] = 0.f;
  if (i < N) { mx[i] = -INFINITY; z[i] = 0.f; }
}

// ---------------- edge kernel 2: exp + denominator ----------------
__global__ void k_edge_ex(const int* __restrict__ dstv, const float* __restrict__ logit,
                          const float* __restrict__ cutb, const float* __restrict__ mx,
                          float* __restrict__ ex, float* __restrict__ z, int E) {
  int e = blockIdx.x * blockDim.x + threadIdx.x;
  if (e >= E) return;
  int t = dstv[e];
  float m = mx[t];
  if (m == -INFINITY) m = 0.f;
  float v = cutb[e] * __expf(logit[e] - m);
  ex[e] = v;
  atomicAdd(&z[t], v);
}

// ---------------- edge kernel 1: K path + logits (LDS-staged weights) ----------------
// 256 thr = 4 waves, 64 edges, wave wv owns M-tile wv.
// 18 tiles, 9 phases x 2 tiles; waves 0,1 stage.
__global__ void __launch_bounds__(256)
k_edge_k(const float* __restrict__ pos, const float* __restrict__ x,
         const float* __restrict__ q,
         const float* __restrict__ fck1, const unsigned short* __restrict__ wtk,
         const float* __restrict__ dot0, const float* __restrict__ dot1,
         const int* __restrict__ srcv, const int* __restrict__ dstv,
         float* __restrict__ logit, float* __restrict__ cutb,
         float* __restrict__ mx, int E) {
  __shared__ alignas(16) unsigned short h_lds[64 * 72];
  __shared__ alignas(16) unsigned short wbuf[2 * 2 * 1024];  // 2 buf x 2 tiles
  __shared__ float fS[48][64];   // fs 0..15 | fv 16..39 | vy 40..47
  __shared__ float y1A[64][4];
  __shared__ float qdA[64][8];
  __shared__ float qvA[64][12];
  __shared__ int dstA[64];

  const int tid = threadIdx.x;
  const int wv = __builtin_amdgcn_readfirstlane(tid >> 6);
  const int lane = tid & 63;
  const int e0 = blockIdx.x * 64;
  const int eL = e0 + lane;
  const bool valid = eL < E;
  const bool ldr = (wv < 2);

  // phase-0 weight preload (tiles 0,1) issued before the long prologue
  uint4 pre0, pre1;
  if (ldr) {
    const unsigned short* gs = wtk + wv * 1024 + lane * 8;
    pre0 = *(const uint4*)(gs);
    pre1 = *(const uint4*)(gs + 512);
  }

  int s = valid ? srcv[eL] : 0, t = valid ? dstv[eL] : 0;

  float y1v[3], d;
  {
    float vx = pos[s * 3 + 0] - pos[t * 3 + 0];
    float vy_ = pos[s * 3 + 1] - pos[t * 3 + 1];
    float vz = pos[s * 3 + 2] - pos[t * 3 + 2];
    d = sqrtf(vx * vx + vy_ * vy_ + vz * vz + 1e-24f);
    float inv = SQ3F / d;
    y1v[0] = vx * inv; y1v[1] = vy_ * inv; y1v[2] = vz * inv;
  }
  float emb[16];
  edge_emb(d, emb);
  {
    float h[16];
    radial_hidden16(fck1, emb, wv, h);
    pack16(&h_lds[lane * 72 + 16 * wv], h);
  }

  if (wv == 0) {
    const float* xs = x + s * 40;
    float fvl[24];
#pragma unroll
    for (int i = 0; i < 16; ++i) fS[i][lane] = xs[i];
#pragma unroll
    for (int i = 0; i < 24; ++i) { fvl[i] = xs[16 + i]; fS[16 + i][lane] = fvl[i]; }
#pragma unroll
    for (int u = 0; u < 8; ++u)
      fS[40 + u][lane] = (fvl[u * 3] * y1v[0] + fvl[u * 3 + 1] * y1v[1] +
                          fvl[u * 3 + 2] * y1v[2]) * INV_SQ3F;
    y1A[lane][0] = y1v[0]; y1A[lane][1] = y1v[1]; y1A[lane][2] = y1v[2];
    dstA[lane] = t;
    if (valid) {
      float uu = 10.0f * (1.0f - 0.5f * d);
      cutb[eL] = (uu > 0.f) ? __expf(-1.0f / fmaxf(uu, 1e-9f)) : 0.f;
    }
    const float* qd_ = q + t * 20;
    float qs_[8], qv_[12];
#pragma unroll
    for (int u = 0; u < 8; ++u) qs_[u] = qd_[u];
#pragma unroll
    for (int i = 0; i < 12; ++i) qv_[i] = qd_[8 + i];
#pragma unroll
    for (int v = 0; v < 8; ++v) {
      float a = 0.f;
#pragma unroll
      for (int u = 0; u < 8; ++u) a += qs_[u] * dot0[u * 8 + v];
      qdA[lane][v] = a * (FAN_DOT * FAN_TP);
    }
#pragma unroll
    for (int v = 0; v < 4; ++v)
#pragma unroll
      for (int i = 0; i < 3; ++i) {
        float a = 0.f;
#pragma unroll
        for (int u = 0; u < 4; ++u) a += qv_[u * 3 + i] * dot1[u * 4 + v];
        qvA[lane][v * 3 + i] = a * (FAN_DOT * INV_SQ3F);
      }
  }
  if (ldr) {
    unsigned short* wd = wbuf + wv * 1024 + lane * 8;
    *(uint4*)(wd) = pre0;
    *(uint4*)(wd + 512) = pre1;
  }
  __syncthreads();

  const int c = lane & 15, g = lane >> 4;
  const int erow = 16 * wv + 4 * g;

  bf16x8 a0 = __builtin_bit_cast(bf16x8, *(const uint4*)&h_lds[(16 * wv + c) * 72 + 8 * g]);
  bf16x8 a1 = __builtin_bit_cast(bf16x8, *(const uint4*)&h_lds[(16 * wv + c) * 72 + 32 + 8 * g]);

  float ksp[4] = {0.f, 0.f, 0.f, 0.f};
  float a2p[4] = {0.f, 0.f, 0.f, 0.f};
  float a3p[4][3] = {{0.f}};

#pragma unroll 1
  for (int p = 0; p < 9; ++p) {
    uint4 nb0, nb1;
    const bool hasNext = (p < 8) && ldr;
    if (hasNext) {
      const unsigned short* gs = wtk + (2 * (p + 1) + wv) * 1024 + lane * 8;
      nb0 = *(const uint4*)(gs);
      nb1 = *(const uint4*)(gs + 512);
    }
    const unsigned short* wb = wbuf + (p & 1) * 2048;
#pragma unroll
    for (int t2 = 0; t2 < 2; ++t2) {
      int T = 2 * p + t2;
      f32x4 acc = gemm2_lds(wb + t2 * 1024, c, g, a0, a1);
      if (T < 8) {
        int u = 2 * T + (c >> 3);
#pragma unroll
        for (int j = 0; j < 4; ++j) ksp[j] += fS[u][erow + j] * acc[j];
      } else if (T < 12) {
        int u = 4 * (T - 8) + (c >> 2);
#pragma unroll
        for (int j = 0; j < 4; ++j) a2p[j] += fS[u][erow + j] * acc[j];
      } else if (T < 14) {
        int u = 4 * (T - 12) + (c >> 2);
#pragma unroll
        for (int j = 0; j < 4; ++j)
#pragma unroll
          for (int i = 0; i < 3; ++i) a3p[j][i] += fS[16 + u * 3 + i][erow + j] * acc[j];
      } else {
        int u = 2 * (T - 14) + (c >> 3);
#pragma unroll
        for (int j = 0; j < 4; ++j) ksp[j] += fS[40 + u][erow + j] * acc[j];
      }
    }
    if (hasNext) {
      unsigned short* wd = wbuf + ((p + 1) & 1) * 2048 + wv * 1024 + lane * 8;
      *(uint4*)(wd) = nb0;
      *(uint4*)(wd + 512) = nb1;
    }
    __syncthreads();
  }

  float ksf[4], a2f[4], a3f[4][3];
#pragma unroll
  for (int j = 0; j < 4; ++j) ksf[j] = ksp[j] + __shfl_xor(ksp[j], 8);
#pragma unroll
  for (int j = 0; j < 4; ++j) {
    float v = a2p[j] + __shfl_xor(a2p[j], 4);
    a2f[j] = v + __shfl_xor(v, 8);
  }
#pragma unroll
  for (int j = 0; j < 4; ++j)
#pragma unroll
    for (int i = 0; i < 3; ++i) {
      float v = a3p[j][i] + __shfl_xor(a3p[j][i], 4);
      a3f[j][i] = v + __shfl_xor(v, 8);
    }

  float lgp[4];
#pragma unroll
  for (int j = 0; j < 4; ++j) {
    float a = 0.f;
    int er = erow + j;
    if (c < 8) {
      a = ksf[j] * qdA[er][c];
    } else if (c < 12) {
      int w = c - 8;
#pragma unroll
      for (int i = 0; i < 3; ++i)
        a += (a2f[j] * y1A[er][i] * FAN_TP + a3f[j][i] * FAN_TP_V) * qvA[er][w * 3 + i];
    }
    lgp[j] = a;
  }
#pragma unroll
  for (int j = 0; j < 4; ++j) {
    lgp[j] += __shfl_xor(lgp[j], 1);
    lgp[j] += __shfl_xor(lgp[j], 2);
    lgp[j] += __shfl_xor(lgp[j], 4);
    lgp[j] += __shfl_xor(lgp[j], 8);
  }
  if (c == 0) {
#pragma unroll
    for (int j = 0; j < 4; ++j) {
      int ee = e0 + erow + j;
      if (ee < E) {
        logit[ee] = lgp[j];
        atomicMaxF(&mx[dstA[erow + j]], lgp[j]);
      }
    }
  }
}

// ---------------- edge kernel 3: V path + scatter (LDS-staged weights) ----------------
// 36 tiles, 18 phases x 2 tiles (8KB wbuf -> 31KB LDS, 5 blocks/CU); waves 0,1 stage.
__global__ void __launch_bounds__(256)
k_edge_v(const float* __restrict__ pos, const float* __restrict__ x,
         const float* __restrict__ fcv1, const unsigned short* __restrict__ wtv,
         const int* __restrict__ srcv, const int* __restrict__ dstv,
         const float* __restrict__ ex, const float* __restrict__ z,
         float* __restrict__ agg, int E) {
  __shared__ alignas(16) unsigned short h_lds[64 * 72];
  __shared__ alignas(16) unsigned short wbuf[2 * 2 * 1024];  // 2 buf x 2 tiles
  __shared__ float fS[48][64];
  __shared__ float y1A[64][4];
  __shared__ float wgtA[64];
  __shared__ int dstA[64];

  const int tid = threadIdx.x;
  const int wv = __builtin_amdgcn_readfirstlane(tid >> 6);
  const int lane = tid & 63;
  const int e0 = blockIdx.x * 64;
  const int eL = e0 + lane;
  const bool valid = eL < E;
  const bool ldr = (wv < 2);

  // phase-0 weight preload (tiles 0,1)
  uint4 pre0, pre1;
  if (ldr) {
    const unsigned short* gs = wtv + wv * 1024 + lane * 8;
    pre0 = *(const uint4*)(gs);
    pre1 = *(const uint4*)(gs + 512);
  }

  int s = valid ? srcv[eL] : 0, t = valid ? dstv[eL] : 0;

  float y1v[3], d;
  {
    float vx = pos[s * 3 + 0] - pos[t * 3 + 0];
    float vy_ = pos[s * 3 + 1] - pos[t * 3 + 1];
    float vz = pos[s * 3 + 2] - pos[t * 3 + 2];
    d = sqrtf(vx * vx + vy_ * vy_ + vz * vz + 1e-24f);
    float inv = SQ3F / d;
    y1v[0] = vx * inv; y1v[1] = vy_ * inv; y1v[2] = vz * inv;
  }
  float emb[16];
  edge_emb(d, emb);
  {
    float h[16];
    radial_hidden16(fcv1, emb, wv, h);
    pack16(&h_lds[lane * 72 + 16 * wv], h);
  }

  if (wv == 0) {
    const float* xs = x + s * 40;
    float fvl[24];
#pragma unroll
    for (int i = 0; i < 16; ++i) fS[i][lane] = xs[i];
#pragma unroll
    for (int i = 0; i < 24; ++i) { fvl[i] = xs[16 + i]; fS[16 + i][lane] = fvl[i]; }
#pragma unroll
    for (int u = 0; u < 8; ++u)
      fS[40 + u][lane] = (fvl[u * 3] * y1v[0] + fvl[u * 3 + 1] * y1v[1] +
                          fvl[u * 3 + 2] * y1v[2]) * INV_SQ3F;
    y1A[lane][0] = y1v[0]; y1A[lane][1] = y1v[1]; y1A[lane][2] = y1v[2];
    dstA[lane] = t;
    float zz = z[t];
    zz = (zz == 0.f) ? 1.f : zz;
    float alpha = (valid ? ex[eL] : 0.f) / zz;
    wgtA[lane] = sqrtf(alpha + 1e-12f);
  }
  if (ldr) {
    unsigned short* wd = wbuf + wv * 1024 + lane * 8;
    *(uint4*)(wd) = pre0;
    *(uint4*)(wd + 512) = pre1;
  }
  __syncthreads();

  const int c = lane & 15, g = lane >> 4;
  const int erow = 16 * wv + 4 * g;

  bf16x8 a0 = __builtin_bit_cast(bf16x8, *(const uint4*)&h_lds[(16 * wv + c) * 72 + 8 * g]);
  bf16x8 a1 = __builtin_bit_cast(bf16x8, *(const uint4*)&h_lds[(16 * wv + c) * 72 + 32 + 8 * g]);

  float vs[4] = {0.f, 0.f, 0.f, 0.f};
  float b2[4] = {0.f, 0.f, 0.f, 0.f};
  float b3[4][3] = {{0.f}};

#pragma unroll 1
  for (int p = 0; p < 18; ++p) {
    uint4 nb0, nb1;
    const bool hasNext = (p < 17) && ldr;
    if (hasNext) {
      const unsigned short* gs = wtv + (2 * (p + 1) + wv) * 1024 + lane * 8;
      nb0 = *(const uint4*)(gs);
      nb1 = *(const uint4*)(gs + 512);
    }
    const unsigned short* wb = wbuf + (p & 1) * 2048;
#pragma unroll
    for (int t2 = 0; t2 < 2; ++t2) {
      int T = 2 * p + t2;
      f32x4 acc = gemm2_lds(wb + t2 * 1024, c, g, a0, a1);
      if (T < 16) {
#pragma unroll
        for (int j = 0; j < 4; ++j) vs[j] += fS[T][erow + j] * acc[j];
      } else if (T < 24) {
        int u = 2 * (T - 16) + (c >> 3);
#pragma unroll
        for (int j = 0; j < 4; ++j) b2[j] += fS[u][erow + j] * acc[j];
      } else if (T < 28) {
        int u = 2 * (T - 24) + (c >> 3);
#pragma unroll
        for (int j = 0; j < 4; ++j)
#pragma unroll
          for (int i = 0; i < 3; ++i) b3[j][i] += fS[16 + u * 3 + i][erow + j] * acc[j];
      } else {
#pragma unroll
        for (int j = 0; j < 4; ++j) vs[j] += fS[40 + (T - 28)][erow + j] * acc[j];
      }
    }
    if (hasNext) {
      unsigned short* wd = wbuf + ((p + 1) & 1) * 2048 + wv * 1024 + lane * 8;
      *(uint4*)(wd) = nb0;
      *(uint4*)(wd + 512) = nb1;
    }
    __syncthreads();
  }

#pragma unroll
  for (int j = 0; j < 4; ++j) b2[j] += __shfl_xor(b2[j], 8);
#pragma unroll
  for (int j = 0; j < 4; ++j)
#pragma unroll
    for (int i = 0; i < 3; ++i) b3[j][i] += __shfl_xor(b3[j][i], 8);

  // scatter: lane owns col c of 4 edges
#pragma unroll
  for (int j = 0; j < 4; ++j) {
    int er = erow + j;
    int ee = e0 + er;
    if (ee >= E) continue;
    float w = wgtA[er];
    float* at = agg + dstA[er] * 40;
    atomicAdd(&at[c], w * vs[j] * FAN_TP);
    if (c < 8) {
#pragma unroll
      for (int i = 0; i < 2; ++i) {
        float v = b2[j] * y1A[er][i] * FAN_TP + b3[j][i] * FAN_TP_V;
        atomicAdd(&at[16 + c * 3 + i], w * v);
      }
    } else {
      float v = b2[j] * y1A[er][2] * FAN_TP + b3[j][2] * FAN_TP_V;
      atomicAdd(&at[16 + (c - 8) * 3 + 2], w * v);
    }
  }
}

// ---------------- output kernel (fused final x += agg) ----------------
template <bool BF>
__global__ void k_out(const float* __restrict__ x, const float* __restrict__ agg,
                      const float* __restrict__ rb0, const float* __restrict__ rb1,
                      const float* __restrict__ re0, const float* __restrict__ re1,
                      void* __restrict__ out, int N, const int* __restrict__ flag) {
  if ((*flag != 0) != BF) return;
  int n = blockIdx.x * blockDim.x + threadIdx.x;
  if (n >= N) return;
  float xn[40];
#pragma unroll
  for (int i = 0; i < 40; ++i) xn[i] = x[n * 40 + i] + agg[n * 40 + i];
  float b[20], eta[20];
  lin_apply<8, 4>(xn, rb0, rb1, b);
  lin_apply<8, 4>(xn, re0, re1, eta);
  if (BF) {
    __hip_bfloat16* o = (__hip_bfloat16*)out;
#pragma unroll
    for (int j = 0; j < 20; ++j) o[n * 20 + j] = __float2bfloat16(b[j]);
#pragma unroll
    for (int j = 0; j < 20; ++j) o[N * 20 + n * 20 + j] = __float2bfloat16(eta[j]);
  } else {
    float* o = (float*)out;
#pragma unroll
    for (int j = 0; j < 20; ++j) o[n * 20 + j] = b[j];
#pragma unroll
    for (int j = 0; j < 20; ++j) o[N * 20 + n * 20 + j] = eta[j];
  }
}

// ---------------- host ----------------
extern "C" void kernel_launch(void* const* d_in, const int* in_sizes, int n_in,
                              void* d_out, int out_size, void* d_ws, size_t ws_size,
                              hipStream_t stream) {
  float* ws = (float*)d_ws;
  const int N = in_sizes[0] / 40;
  const int E = in_sizes[16];
  const int* src = (const int*)d_in[16];
  const int* dst = (const int*)d_in[17];
  int* flag = (int*)(ws + OFF_FLAG);
  unsigned short* wtv = (unsigned short*)(ws + OFF_WT);
  unsigned short* wtk = (unsigned short*)(ws + OFF_WTK);

  k_detect<<<1, 64, 0, stream>>>((const unsigned int*)d_in[0], flag);

  CvtArgs ca;
  const int order[16] = {2, 3, 4, 5, 6, 7, 8, 9, 10, 11, 12, 13, 14, 15, 0, 1};
  const int offs[16] = {OFF_LIN0, OFF_LIN1, OFF_HQ0, OFF_HQ1, OFF_FCK1, OFF_FCK2,
                        OFF_FCV1, OFF_FCV2, OFF_DOT0, OFF_DOT1, OFF_RB0, OFF_RB1,
                        OFF_RE0, OFF_RE1, OFF_F, OFF_POS};
  for (int i = 0; i < 16; ++i) {
    ca.src[i] = d_in[order[i]];
    ca.n[i] = in_sizes[order[i]];
    ca.off[i] = offs[i];
  }
  k_cvt<false><<<512, 256, 0, stream>>>(ca, ws, flag);
  k_cvt<true><<<512, 256, 0, stream>>>(ca, ws, flag);
  k_wt<<<(2 * 36864 + 255) / 256, 256, 0, stream>>>(ws + OFF_FCV2, wtv);
  k_wtk<<<(2 * 18432 + 255) / 256, 256, 0, stream>>>(ws + OFF_FCK2, wtk);

  float* x = ws + OFF_X;
  float* q = ws + OFF_Q;
  float* mx = ws + OFF_MX;
  float* z = ws + OFF_Z;
  float* agg = ws + OFF_AGG;
  float* logit = ws + OFF_LOGIT;
  float* cutb = ws + OFF_CUT;
  float* exb = ws + OFF_EX;
  const float* pos = ws + OFF_POS;

  const int nodeBlocks = (N + 255) / 256;
  const int vecBlocks = (N * 40 + 255) / 256;
  const int edgeBlocks = (E + 255) / 256;
  const int eb64 = (E + 63) / 64;   // block = 64 edges, 256 threads

  k_lin_in<<<nodeBlocks, 256, 0, stream>>>(ws + OFF_F, ws + OFF_LIN0, ws + OFF_LIN1, x, N);

  for (int l = 0; l < 2; ++l) {
    // x += agg(prev layer) fused into q computation; must precede k_init's agg clear
    k_qup<<<nodeBlocks, 256, 0, stream>>>(x, agg, ws + OFF_HQ0 + l * 128,
                                          ws + OFF_HQ1 + l * 32, q, N, l > 0 ? 1 : 0);
    k_init<<<vecBlocks, 256, 0, stream>>>(mx, z, agg, N);
    k_edge_k<<<eb64, 256, 0, stream>>>(
        pos, x, q, ws + OFF_FCK1 + l * 1024, wtk + l * 18432,
        ws + OFF_DOT0 + l * 64, ws + OFF_DOT1 + l * 16, src, dst, logit, cutb, mx, E);
    k_edge_ex<<<edgeBlocks, 256, 0, stream>>>(dst, logit, cutb, mx, exb, z, E);
    k_edge_v<<<eb64, 256, 0, stream>>>(
        pos, x, ws + OFF_FCV1 + l * 1024, wtv + l * 36864, src, dst, exb, z, agg, E);
  }

  k_out<false><<<nodeBlocks, 256, 0, stream>>>(x, agg, ws + OFF_RB0, ws + OFF_RB1,
                                               ws + OFF_RE0, ws + OFF_RE1, d_out, N, flag);
  k_out<true><<<nodeBlocks, 256, 0, stream>>>(x, agg, ws + OFF_RB0, ws + OFF_RB1,
                                              ws + OFF_RE0, ws + OFF_RE1, d_out, N, flag);
}